// Round 9
// baseline (332.991 us; speedup 1.0000x reference)
//
#include <hip/hip_runtime.h>
#include <math.h>

#define BB 8
#define TT 1024
#define CC 64

typedef float f32x4 __attribute__((ext_vector_type(4)));
typedef short short8 __attribute__((ext_vector_type(8)));
typedef unsigned int u32x4 __attribute__((ext_vector_type(4)));
typedef unsigned short u16;

static __device__ __forceinline__ u16 f2bf(float f) {
    union { float f; unsigned int u; } v; v.f = f;
    unsigned int r = v.u + 0x7fffu + ((v.u >> 16) & 1u);
    return (u16)(r >> 16);
}
static __device__ __forceinline__ float bf2f(u16 h) {
    union { unsigned int u; float f; } v; v.u = ((unsigned int)h) << 16; return v.f;
}
static __device__ __forceinline__ short8 pack8(const float* p) {
    float4 a = *(const float4*)p;
    float4 b = *(const float4*)(p + 4);
    short8 r;
    r[0] = (short)f2bf(a.x); r[1] = (short)f2bf(a.y); r[2] = (short)f2bf(a.z); r[3] = (short)f2bf(a.w);
    r[4] = (short)f2bf(b.x); r[5] = (short)f2bf(b.y); r[6] = (short)f2bf(b.z); r[7] = (short)f2bf(b.w);
    return r;
}

#define MFMA16(a, b, c) __builtin_amdgcn_mfma_f32_16x16x32_bf16((a), (b), (c), 0, 0, 0)

// Workspace layout (bytes)
#define OFF_QBF      ((size_t)0)             // q pre-scaled by 0.125
#define OFF_KBF      ((size_t)1048576)
#define OFF_VT       ((size_t)2097152)       // [b][c][t]
#define OFF_EKP      ((size_t)3145728)       // 1088*64 bf16 (rows d=-32..1055)
#define OFF_EVT      ((size_t)3284992)       // 64*1088 bf16 (cols d=-32..1055)
#define OFF_WPROJ    ((size_t)3424256)       // 64*64 bf16
#define OFF_YP       ((size_t)3432448)       // 8*64*8*1024 fp32 = 16777216
#define OFF_LP       ((size_t)20209664)      // 8*64*8*16 fp32 = 262144
#define OFF_CNT      ((size_t)20471808)      // 8*64 int = 2048
#define WS_NEED      ((size_t)20473856)

// ---------------------------------------------------------------------------
// K1: qkv + prep. Grid (576, 3): x<512 -> qkv row-tile, y = oc group; one oc
// chunk per wave. x>=512 & y==0 -> pad fills. (Verified R6-R8 structure.)
// ---------------------------------------------------------------------------
__global__ __launch_bounds__(256) void qkv_prep_kernel(const float* __restrict__ x,
                                                       const float* __restrict__ Wqkv,
                                                       const float* __restrict__ bqkv,
                                                       const float* __restrict__ embk,
                                                       const float* __restrict__ embv,
                                                       const float* __restrict__ Wproj,
                                                       u16* __restrict__ q_bf,
                                                       u16* __restrict__ k_bf,
                                                       u16* __restrict__ vT_bf,
                                                       u16* __restrict__ embk_pad,
                                                       u16* __restrict__ embvT_pad,
                                                       u16* __restrict__ Wproj_bf) {
    const int blk = blockIdx.x;
    const int grp = blockIdx.y;
    const int tid = threadIdx.x;

    if (blk >= 512) {
        if (grp != 0) return;
        const int idx0 = (blk - 512) * 256 + tid;
        const int stride = 64 * 256;
        for (int i = idx0; i < 1088 * CC; i += stride) {
            int r = i >> 6, c = i & 63, d = r - 32;
            embk_pad[i] = (d >= 0 && d < TT) ? f2bf(embk[d * CC + c]) : (u16)0;
        }
        for (int i = idx0; i < CC * 1088; i += stride) {
            int c = i / 1088, col = i - c * 1088, d = col - 32;
            embvT_pad[i] = (d >= 0 && d < TT) ? f2bf(embv[d * CC + c]) : (u16)0;
        }
        for (int i = idx0; i < CC * CC; i += stride) Wproj_bf[i] = f2bf(Wproj[i]);
        return;
    }

    const int w = tid >> 6, lane = tid & 63, quad = lane >> 4, l15 = lane & 15;
    const int row0 = blk * 16;
    const int oc = grp * 4 + w;                 // 0..11
    __shared__ float vt[4][16][17];

    const float* xr = x + (size_t)(row0 + l15) * CC + quad * 8;
    short8 a0 = pack8(xr);
    short8 a1 = pack8(xr + 32);

    const float* wr = Wqkv + (size_t)(oc * 16 + l15) * CC + quad * 8;
    short8 b0 = pack8(wr);
    short8 b1 = pack8(wr + 32);
    f32x4 acc = {0.f, 0.f, 0.f, 0.f};
    acc = MFMA16(a0, b0, acc);
    acc = MFMA16(a1, b1, acc);
    const float bias = bqkv[oc * 16 + l15];

    if (oc < 4) {
        const int c = oc * 16 + l15;
        #pragma unroll
        for (int r = 0; r < 4; ++r)
            q_bf[(size_t)(row0 + quad * 4 + r) * CC + c] = f2bf((acc[r] + bias) * 0.125f);
    } else if (oc < 8) {
        const int c = (oc - 4) * 16 + l15;
        #pragma unroll
        for (int r = 0; r < 4; ++r)
            k_bf[(size_t)(row0 + quad * 4 + r) * CC + c] = f2bf(acc[r] + bias);
    } else {
        #pragma unroll
        for (int r = 0; r < 4; ++r) vt[w][quad * 4 + r][l15] = acc[r] + bias;
        const int c_l = lane >> 2;
        const int tbase = (lane & 3) * 4;
        const int b = row0 >> 10, t0v = row0 & (TT - 1);
        u16 p[4];
        #pragma unroll
        for (int tt2 = 0; tt2 < 4; ++tt2) p[tt2] = f2bf(vt[w][tbase + tt2][c_l]);
        unsigned long long pk = (unsigned long long)p[0] | ((unsigned long long)p[1] << 16)
                              | ((unsigned long long)p[2] << 32) | ((unsigned long long)p[3] << 48);
        *(unsigned long long*)&vT_bf[(size_t)(b * CC + (oc - 8) * 16 + c_l) * TT + t0v + tbase] = pk;
    }
}

// ---------------------------------------------------------------------------
// K2: attention partials + fused last-block normalize/proj.
// Grid (288, 8): block x -> (tt, slot); each of the 4 waves does ONE s-tile
// (verified R8 body: shfl-band, fixed-max softmax, deterministic slots).
// After storing its slot, each block takes a device-scope ticket for (b,tt);
// the block drawing ticket nslots-1 merges all slots (L2-hot), normalizes,
// and runs the Wproj MFMA epilogue. Counters zeroed via hipMemsetAsync.
// ---------------------------------------------------------------------------
#define WBSTRIDE 4160   // per-wave LDS: pt(1280) + a2(2304) = 3584; merge 4096

__global__ __launch_bounds__(256) void attn_part_kernel(const u16* __restrict__ q_bf,
                                                        const u16* __restrict__ k_bf,
                                                        const u16* __restrict__ vT_bf,
                                                        const u16* __restrict__ embk_pad,
                                                        const u16* __restrict__ embvT_pad,
                                                        const u16* __restrict__ Wproj_bf,
                                                        const float* __restrict__ bproj,
                                                        float* __restrict__ Ypart,
                                                        float* __restrict__ Lpart,
                                                        int* __restrict__ cnt,
                                                        float* __restrict__ out) {
    const int b = blockIdx.y;
    // map flat x -> (tt, slot): per-tile slot count = ceil(nst/4) = ((tt>>1)+4)>>2
    int xx = blockIdx.x;
    int tt = 0, slot = 0;
    for (tt = 0; tt < 64; ++tt) {
        const int c = ((tt >> 1) + 4) >> 2;
        if (xx < c) { slot = xx; break; }
        xx -= c;
    }
    const int t0 = tt * 16;
    const int nst = (t0 >> 5) + 1;
    const int nslots = ((tt >> 1) + 4) >> 2;

    const int tid = threadIdx.x;
    const int w = tid >> 6, lane = tid & 63, quad = lane >> 4, l15 = lane & 15;
    const int st = slot * 4 + w;
    const bool active = (st < nst);

    __shared__ __align__(16) char wbuf[4][WBSTRIDE];
    __shared__ float lpart[4][16];
    __shared__ int ticket_s;

    u16* pt = (u16*)(wbuf[w]);                    // 16*40 bf16
    u16* a2 = (u16*)(wbuf[w] + 1280);             // 16*72 bf16 (skewed P)

    f32x4 acc[4];
    #pragma unroll
    for (int nb = 0; nb < 4; ++nb) acc[nb] = (f32x4){0.f, 0.f, 0.f, 0.f};
    float rsum[4] = {0.f, 0.f, 0.f, 0.f};

    if (active) {
        const int s0 = st * 32;

        // hoisted Q fragments (q pre-scaled by 0.125)
        const u16* qrow = q_bf + (size_t)((b << 10) + t0 + l15) * CC;
        short8 aq0 = *(const short8*)(qrow + quad * 8);
        short8 aq1 = *(const short8*)(qrow + 32 + quad * 8);

        // ---- content scores: 16x32 tile ----
        f32x4 sc[2];
        #pragma unroll
        for (int cb = 0; cb < 2; ++cb) {
            const u16* krow = k_bf + (size_t)((b << 10) + s0 + cb * 16 + l15) * CC;
            short8 kb0 = *(const short8*)(krow + quad * 8);
            short8 kb1 = *(const short8*)(krow + 32 + quad * 8);
            f32x4 a = {0.f, 0.f, 0.f, 0.f};
            a = MFMA16(aq0, kb0, a);
            a = MFMA16(aq1, kb1, a);
            sc[cb] = a;
        }

        // ---- relative band: 3 MFMAs kept in C-layout registers ----
        const int dbase = t0 - s0 - 31;
        f32x4 bnd[3];
        #pragma unroll
        for (int nb = 0; nb < 3; ++nb) {
            const u16* erow = embk_pad + (size_t)(dbase + 32 + nb * 16 + l15) * CC;
            short8 eb0 = *(const short8*)(erow + quad * 8);
            short8 eb1 = *(const short8*)(erow + 32 + quad * 8);
            f32x4 a = {0.f, 0.f, 0.f, 0.f};
            a = MFMA16(aq0, eb0, a);
            a = MFMA16(aq1, eb1, a);
            bnd[nb] = a;
        }

        // ---- band via cross-lane shuffles + masked p = exp(score) ----
        u16 pb0[4], pb1[4];
        #pragma unroll
        for (int r = 0; r < 4; ++r) {
            const int i = quad * 4 + r;
            const int u0 = 31 + i - l15;
            const int src = (quad << 4) | (u0 & 15);
            const float v0 = __shfl(bnd[0][r], src, 64);
            const float v1 = __shfl(bnd[1][r], src, 64);
            const float v2 = __shfl(bnd[2][r], src, 64);
            const bool hi = (u0 >= 32);
            {   // cb = 0: j = l15
                const float rb = hi ? v2 : v1;
                const int d = t0 - s0 + i - l15;
                float pv = (d >= 0) ? __expf(sc[0][r] + rb) : 0.f;
                pb0[r] = f2bf(pv);
                rsum[r] += bf2f(pb0[r]);
            }
            {   // cb = 1: j = 16+l15
                const float rb = hi ? v1 : v0;
                const int d = t0 - s0 + i - 16 - l15;
                float pv = (d >= 0) ? __expf(sc[1][r] + rb) : 0.f;
                pb1[r] = f2bf(pv);
                rsum[r] += bf2f(pb1[r]);
            }
        }

        // ---- write P: row-major (pt) and skewed (a2); in-wave DS order ----
        u32x4 z = {0u, 0u, 0u, 0u};
        #pragma unroll
        for (int e = 0; e < 3; ++e) {              // 144 u32x4 = 16*72 u16
            int idx = lane + e * 64;
            if (idx < 144) ((u32x4*)a2)[idx] = z;
        }
        #pragma unroll
        for (int r = 0; r < 4; ++r) {
            const int i = quad * 4 + r;
            pt[i * 40 + l15] = pb0[r];
            pt[i * 40 + 16 + l15] = pb1[r];
            a2[i * 72 + (32 + i - l15)] = pb0[r];
            a2[i * 72 + (16 + i - l15)] = pb1[r];
        }

        // ---- y1 += P @ V ----
        short8 aP = *(const short8*)(pt + l15 * 40 + quad * 8);
        #pragma unroll
        for (int nb = 0; nb < 4; ++nb) {
            const u16* vrow = vT_bf + ((size_t)(b * CC + nb * 16 + l15) << 10) + s0;
            short8 bv = *(const short8*)(vrow + quad * 8);
            acc[nb] = MFMA16(aP, bv, acc[nb]);
        }

        // ---- y2 += skew(P) @ embv band ----
        const int dcol0 = t0 - s0;
        #pragma unroll
        for (int kk = 0; kk < 2; ++kk) {
            short8 a2f = *(const short8*)(a2 + l15 * 72 + kk * 32 + quad * 8);
            #pragma unroll
            for (int nb = 0; nb < 4; ++nb) {
                const u16* erow = embvT_pad + (size_t)(nb * 16 + l15) * 1088 + dcol0 + kk * 32 + quad * 8;
                short8 be = *(const short8*)erow;
                acc[nb] = MFMA16(a2f, be, acc[nb]);
            }
        }
    }

    // ---- per-wave row-sum reduction ----
    #pragma unroll
    for (int msk = 1; msk < 16; msk <<= 1)
        #pragma unroll
        for (int r = 0; r < 4; ++r) rsum[r] += __shfl_xor(rsum[r], msk, 64);
    if (l15 == 0) {
        #pragma unroll
        for (int r = 0; r < 4; ++r) lpart[w][quad * 4 + r] = rsum[r];
    }

    // ---- wave partial Y -> unioned per-wave LDS region ----
    float* ypw = (float*)(wbuf[w]);
    #pragma unroll
    for (int nb = 0; nb < 4; ++nb)
        #pragma unroll
        for (int r = 0; r < 4; ++r)
            ypw[(quad * 4 + r) * 64 + nb * 16 + l15] = acc[nb][r];
    __syncthreads();

    // ---- merge 4 wave partials, store slot (unnormalized) ----
    const int i4 = tid >> 4, c04 = (tid * 4) & 63;
    const size_t sbase = ((size_t)((b * 64 + tt) * 8 + slot)) << 10;
    {
        float4 Y;
        Y.x = ((float*)(wbuf[0]))[i4 * 64 + c04]     + ((float*)(wbuf[1]))[i4 * 64 + c04]
            + ((float*)(wbuf[2]))[i4 * 64 + c04]     + ((float*)(wbuf[3]))[i4 * 64 + c04];
        Y.y = ((float*)(wbuf[0]))[i4 * 64 + c04 + 1] + ((float*)(wbuf[1]))[i4 * 64 + c04 + 1]
            + ((float*)(wbuf[2]))[i4 * 64 + c04 + 1] + ((float*)(wbuf[3]))[i4 * 64 + c04 + 1];
        Y.z = ((float*)(wbuf[0]))[i4 * 64 + c04 + 2] + ((float*)(wbuf[1]))[i4 * 64 + c04 + 2]
            + ((float*)(wbuf[2]))[i4 * 64 + c04 + 2] + ((float*)(wbuf[3]))[i4 * 64 + c04 + 2];
        Y.w = ((float*)(wbuf[0]))[i4 * 64 + c04 + 3] + ((float*)(wbuf[1]))[i4 * 64 + c04 + 3]
            + ((float*)(wbuf[2]))[i4 * 64 + c04 + 3] + ((float*)(wbuf[3]))[i4 * 64 + c04 + 3];
        *(float4*)&Ypart[sbase + (size_t)tid * 4] = Y;
    }
    if (tid < 16)
        Lpart[((size_t)((b * 64 + tt) * 8 + slot)) * 16 + tid] =
            lpart[0][tid] + lpart[1][tid] + lpart[2][tid] + lpart[3][tid];
    __syncthreads();   // drains vmcnt: all slot stores complete before ticket

    // ---- last-block ticket: winner merges + normalizes + projects ----
    if (tid == 0) {
        __threadfence();                          // release: slot data -> device scope
        ticket_s = atomicAdd(&cnt[b * 64 + tt], 1);
    }
    __syncthreads();
    if (ticket_s != nslots - 1) return;
    __threadfence();                              // acquire: see other slots' data

    const size_t base = ((size_t)((b * 64 + tt) * 8)) << 10;
    float4 Y = {0.f, 0.f, 0.f, 0.f};
    for (int s = 0; s < nslots; ++s) {
        float4 v = *(const float4*)&Ypart[base + ((size_t)s << 10) + (size_t)tid * 4];
        Y.x += v.x; Y.y += v.y; Y.z += v.z; Y.w += v.w;
    }
    float* Ls = lpart[0];
    if (tid < 16) {
        float L = 0.f;
        for (int s = 0; s < nslots; ++s)
            L += Lpart[((size_t)((b * 64 + tt) * 8 + s)) * 16 + tid];
        Ls[tid] = L;
    }
    __syncthreads();

    u16* yA = (u16*)(wbuf[1]);                    // 2 KB scratch for bf16 y
    {
        const float inv = 1.0f / Ls[i4];
        u16 y4[4] = { f2bf(Y.x * inv), f2bf(Y.y * inv), f2bf(Y.z * inv), f2bf(Y.w * inv) };
        *(unsigned long long*)&yA[i4 * 64 + c04] =
            (unsigned long long)y4[0] | ((unsigned long long)y4[1] << 16)
          | ((unsigned long long)y4[2] << 32) | ((unsigned long long)y4[3] << 48);
    }
    __syncthreads();

    // proj: wave w -> output cols w*16 .. +15
    short8 a0 = *(const short8*)(yA + l15 * 64 + quad * 8);
    short8 a1 = *(const short8*)(yA + l15 * 64 + 32 + quad * 8);
    const u16* wrow = Wproj_bf + (size_t)(w * 16 + l15) * CC;
    short8 wb0 = *(const short8*)(wrow + quad * 8);
    short8 wb1 = *(const short8*)(wrow + 32 + quad * 8);
    f32x4 o = {0.f, 0.f, 0.f, 0.f};
    o = MFMA16(a0, wb0, o);
    o = MFMA16(a1, wb1, o);
    const float bias = bproj[w * 16 + l15];
    #pragma unroll
    for (int r = 0; r < 4; ++r)
        out[(size_t)((b << 10) + t0 + quad * 4 + r) * CC + w * 16 + l15] = o[r] + bias;
}

// ===========================================================================
// Fallback path (round-1 verified fp32 kernels) — used if ws_size < needed.
// ===========================================================================
__global__ __launch_bounds__(192) void qkv_kernel(const float* __restrict__ x,
                                                  const float* __restrict__ Wqkv,
                                                  const float* __restrict__ bqkv,
                                                  float* __restrict__ qkv) {
    __shared__ __align__(16) float xs[CC];
    const int row = blockIdx.x;
    const int j = threadIdx.x;
    if (j < CC) xs[j] = x[row * CC + j];
    __syncthreads();
    const float* w = Wqkv + j * CC;
    float acc = bqkv[j];
    #pragma unroll
    for (int c = 0; c < CC; c += 4) {
        float4 wq = *(const float4*)(w + c);
        float4 xq = *(const float4*)(xs + c);
        acc += wq.x * xq.x + wq.y * xq.y + wq.z * xq.z + wq.w * xq.w;
    }
    qkv[row * 192 + j] = acc;
}

__global__ __launch_bounds__(256) void attn_kernel(const float* __restrict__ qkv,
                                                   const float* __restrict__ embk,
                                                   const float* __restrict__ embv,
                                                   const float* __restrict__ Wproj,
                                                   const float* __restrict__ bproj,
                                                   float* __restrict__ out) {
    __shared__ __align__(16) float qs[CC];
    __shared__ __align__(16) float sc[TT];
    __shared__ float red[256];
    __shared__ float yred[4][CC];
    const int bt = blockIdx.x;
    const int b = bt >> 10, t = bt & (TT - 1);
    const int tid = threadIdx.x;
    if (tid < CC) qs[tid] = qkv[bt * 192 + tid];
    __syncthreads();
    float lmax = -1e30f;
    for (int s = tid; s <= t; s += 256) {
        const float* krow = qkv + (b * TT + s) * 192 + 64;
        const float* erow = embk + (t - s) * CC;
        float acc = 0.f;
        #pragma unroll
        for (int c = 0; c < CC; c += 4) {
            float4 kq = *(const float4*)(krow + c);
            float4 eq = *(const float4*)(erow + c);
            float4 qq = *(const float4*)(qs + c);
            acc += qq.x * (kq.x + eq.x) + qq.y * (kq.y + eq.y)
                 + qq.z * (kq.z + eq.z) + qq.w * (kq.w + eq.w);
        }
        acc *= 0.125f;
        sc[s] = acc;
        lmax = fmaxf(lmax, acc);
    }
    red[tid] = lmax; __syncthreads();
    for (int off = 128; off > 0; off >>= 1) { if (tid < off) red[tid] = fmaxf(red[tid], red[tid + off]); __syncthreads(); }
    const float m = red[0]; __syncthreads();
    float lsum = 0.f;
    for (int s = tid; s <= t; s += 256) { float e = __expf(sc[s] - m); sc[s] = e; lsum += e; }
    red[tid] = lsum; __syncthreads();
    for (int off = 128; off > 0; off >>= 1) { if (tid < off) red[tid] += red[tid + off]; __syncthreads(); }
    const float inv = 1.0f / red[0]; __syncthreads();
    const int c = tid & 63, g = tid >> 6;
    float acc = 0.f;
    for (int s = g; s <= t; s += 4) {
        float p = sc[s];
        float vv = qkv[(b * TT + s) * 192 + 128 + c];
        float ev = embv[(t - s) * CC + c];
        acc += p * (vv + ev);
    }
    yred[g][c] = acc * inv;
    __syncthreads();
    if (tid < CC) qs[tid] = yred[0][tid] + yred[1][tid] + yred[2][tid] + yred[3][tid];
    __syncthreads();
    if (tid < CC) {
        const float* w = Wproj + tid * CC;
        float o = bproj[tid];
        #pragma unroll
        for (int cc2 = 0; cc2 < CC; cc2 += 4) {
            float4 wq = *(const float4*)(w + cc2);
            float4 yq = *(const float4*)(qs + cc2);
            o += wq.x * yq.x + wq.y * yq.y + wq.z * yq.z + wq.w * yq.w;
        }
        out[bt * CC + tid] = o;
    }
}

extern "C" void kernel_launch(void* const* d_in, const int* in_sizes, int n_in,
                              void* d_out, int out_size, void* d_ws, size_t ws_size,
                              hipStream_t stream) {
    const float* x     = (const float*)d_in[0];
    const float* Wqkv  = (const float*)d_in[1];
    const float* bqkv  = (const float*)d_in[2];
    const float* embk  = (const float*)d_in[3];
    const float* embv  = (const float*)d_in[4];
    const float* Wproj = (const float*)d_in[5];
    const float* bproj = (const float*)d_in[6];
    float* out = (float*)d_out;

    if (ws_size < WS_NEED) {
        float* qkv = (float*)d_ws;
        qkv_kernel<<<BB * TT, 192, 0, stream>>>(x, Wqkv, bqkv, qkv);
        attn_kernel<<<BB * TT, 256, 0, stream>>>(qkv, embk, embv, Wproj, bproj, out);
        return;
    }

    char* ws = (char*)d_ws;
    u16* q_bf       = (u16*)(ws + OFF_QBF);
    u16* k_bf       = (u16*)(ws + OFF_KBF);
    u16* vT_bf      = (u16*)(ws + OFF_VT);
    u16* embk_pad   = (u16*)(ws + OFF_EKP);
    u16* embvT_pad  = (u16*)(ws + OFF_EVT);
    u16* Wproj_bf   = (u16*)(ws + OFF_WPROJ);
    float* Ypart    = (float*)(ws + OFF_YP);
    float* Lpart    = (float*)(ws + OFF_LP);
    int*   cnt      = (int*)(ws + OFF_CNT);

    hipMemsetAsync(cnt, 0, 8 * 64 * sizeof(int), stream);
    qkv_prep_kernel<<<dim3(576, 3), 256, 0, stream>>>(x, Wqkv, bqkv, embk, embv, Wproj,
                                                      q_bf, k_bf, vT_bf, embk_pad, embvT_pad, Wproj_bf);
    attn_part_kernel<<<dim3(288, 8), 256, 0, stream>>>(q_bf, k_bf, vT_bf, embk_pad, embvT_pad,
                                                       Wproj_bf, bproj, Ypart, Lpart, cnt, out);
}

// Round 10
// 123.954 us; speedup vs baseline: 2.6864x; 2.6864x over previous
//
#include <hip/hip_runtime.h>
#include <math.h>

#define BB 8
#define TT 1024
#define CC 64

typedef float f32x4 __attribute__((ext_vector_type(4)));
typedef short short8 __attribute__((ext_vector_type(8)));
typedef unsigned int u32x4 __attribute__((ext_vector_type(4)));
typedef unsigned short u16;

static __device__ __forceinline__ u16 f2bf(float f) {
    union { float f; unsigned int u; } v; v.f = f;
    unsigned int r = v.u + 0x7fffu + ((v.u >> 16) & 1u);
    return (u16)(r >> 16);
}
static __device__ __forceinline__ float bf2f(u16 h) {
    union { unsigned int u; float f; } v; v.u = ((unsigned int)h) << 16; return v.f;
}
static __device__ __forceinline__ short8 pack8(const float* p) {
    float4 a = *(const float4*)p;
    float4 b = *(const float4*)(p + 4);
    short8 r;
    r[0] = (short)f2bf(a.x); r[1] = (short)f2bf(a.y); r[2] = (short)f2bf(a.z); r[3] = (short)f2bf(a.w);
    r[4] = (short)f2bf(b.x); r[5] = (short)f2bf(b.y); r[6] = (short)f2bf(b.z); r[7] = (short)f2bf(b.w);
    return r;
}

#define MFMA16(a, b, c) __builtin_amdgcn_mfma_f32_16x16x32_bf16((a), (b), (c), 0, 0, 0)

// Workspace layout (bytes)
#define OFF_QBF      ((size_t)0)             // q pre-scaled by 0.125
#define OFF_KBF      ((size_t)1048576)
#define OFF_VT       ((size_t)2097152)       // [b][c][t]
#define OFF_EKP      ((size_t)3145728)       // 1088*64 bf16 (rows d=-32..1055)
#define OFF_EVT      ((size_t)3284992)       // 64*1088 bf16 (cols d=-32..1055)
#define OFF_WPROJ    ((size_t)3424256)       // 64*64 bf16
#define OFF_YP       ((size_t)3432448)       // 8*1056*1024 fp32 = 34603008
#define OFF_LP       ((size_t)38035456)      // 8*1056*16 fp32 = 540672
#define WS_NEED      ((size_t)38576128)

// NSLOT_TOTAL = sum over tt of nst(tt) = 32*33 = 1056; packed base:
// S(2h) = h*(h+1), S(2h+1) = (h+1)^2.

// ---------------------------------------------------------------------------
// K1: qkv + prep. Grid (576, 3): x<512 -> qkv row-tile, y = oc group; one oc
// chunk per wave. x>=512 & y==0 -> pad fills. (Verified R6-R8 structure.)
// ---------------------------------------------------------------------------
__global__ __launch_bounds__(256) void qkv_prep_kernel(const float* __restrict__ x,
                                                       const float* __restrict__ Wqkv,
                                                       const float* __restrict__ bqkv,
                                                       const float* __restrict__ embk,
                                                       const float* __restrict__ embv,
                                                       const float* __restrict__ Wproj,
                                                       u16* __restrict__ q_bf,
                                                       u16* __restrict__ k_bf,
                                                       u16* __restrict__ vT_bf,
                                                       u16* __restrict__ embk_pad,
                                                       u16* __restrict__ embvT_pad,
                                                       u16* __restrict__ Wproj_bf) {
    const int blk = blockIdx.x;
    const int grp = blockIdx.y;
    const int tid = threadIdx.x;

    if (blk >= 512) {
        if (grp != 0) return;
        const int idx0 = (blk - 512) * 256 + tid;
        const int stride = 64 * 256;
        for (int i = idx0; i < 1088 * CC; i += stride) {
            int r = i >> 6, c = i & 63, d = r - 32;
            embk_pad[i] = (d >= 0 && d < TT) ? f2bf(embk[d * CC + c]) : (u16)0;
        }
        for (int i = idx0; i < CC * 1088; i += stride) {
            int c = i / 1088, col = i - c * 1088, d = col - 32;
            embvT_pad[i] = (d >= 0 && d < TT) ? f2bf(embv[d * CC + c]) : (u16)0;
        }
        for (int i = idx0; i < CC * CC; i += stride) Wproj_bf[i] = f2bf(Wproj[i]);
        return;
    }

    const int w = tid >> 6, lane = tid & 63, quad = lane >> 4, l15 = lane & 15;
    const int row0 = blk * 16;
    const int oc = grp * 4 + w;                 // 0..11
    __shared__ float vt[4][16][17];

    const float* xr = x + (size_t)(row0 + l15) * CC + quad * 8;
    short8 a0 = pack8(xr);
    short8 a1 = pack8(xr + 32);

    const float* wr = Wqkv + (size_t)(oc * 16 + l15) * CC + quad * 8;
    short8 b0 = pack8(wr);
    short8 b1 = pack8(wr + 32);
    f32x4 acc = {0.f, 0.f, 0.f, 0.f};
    acc = MFMA16(a0, b0, acc);
    acc = MFMA16(a1, b1, acc);
    const float bias = bqkv[oc * 16 + l15];

    if (oc < 4) {
        const int c = oc * 16 + l15;
        #pragma unroll
        for (int r = 0; r < 4; ++r)
            q_bf[(size_t)(row0 + quad * 4 + r) * CC + c] = f2bf((acc[r] + bias) * 0.125f);
    } else if (oc < 8) {
        const int c = (oc - 4) * 16 + l15;
        #pragma unroll
        for (int r = 0; r < 4; ++r)
            k_bf[(size_t)(row0 + quad * 4 + r) * CC + c] = f2bf(acc[r] + bias);
    } else {
        #pragma unroll
        for (int r = 0; r < 4; ++r) vt[w][quad * 4 + r][l15] = acc[r] + bias;
        const int c_l = lane >> 2;
        const int tbase = (lane & 3) * 4;
        const int b = row0 >> 10, t0v = row0 & (TT - 1);
        u16 p[4];
        #pragma unroll
        for (int tt2 = 0; tt2 < 4; ++tt2) p[tt2] = f2bf(vt[w][tbase + tt2][c_l]);
        unsigned long long pk = (unsigned long long)p[0] | ((unsigned long long)p[1] << 16)
                              | ((unsigned long long)p[2] << 32) | ((unsigned long long)p[3] << 48);
        *(unsigned long long*)&vT_bf[(size_t)(b * CC + (oc - 8) * 16 + c_l) * TT + t0v + tbase] = pk;
    }
}

// ---------------------------------------------------------------------------
// K2: attention partials, ONE WAVE PER BLOCK (one s-tile each, no barriers).
// Grid (1056, 8): blockIdx.x is the packed (tt, st) slot index; the 64-thread
// block runs the verified R8 body (shfl-band, fixed-max softmax) and stores
// its own unnormalized (Y 16x64 fp32, L 16 fp32) slot. 32 blocks/CU resident
// (VGPR~48, LDS 3.6 KB) for deep latency hiding; zero tail.
// ---------------------------------------------------------------------------
__global__ __launch_bounds__(64) void attn_part_kernel(const u16* __restrict__ q_bf,
                                                       const u16* __restrict__ k_bf,
                                                       const u16* __restrict__ vT_bf,
                                                       const u16* __restrict__ embk_pad,
                                                       const u16* __restrict__ embvT_pad,
                                                       float* __restrict__ Ypart,
                                                       float* __restrict__ Lpart) {
    const int b = blockIdx.y;
    // map packed x -> (tt, st): nst(tt) = (tt>>1)+1
    int xx = blockIdx.x;
    int tt = 0, st = 0;
    for (tt = 0; tt < 64; ++tt) {
        const int c = (tt >> 1) + 1;
        if (xx < c) { st = xx; break; }
        xx -= c;
    }
    const int t0 = tt * 16;
    const int s0 = st * 32;

    const int lane = threadIdx.x, quad = lane >> 4, l15 = lane & 15;

    __shared__ __align__(16) char wbuf[4160];
    u16* pt = (u16*)(wbuf);                       // 16*40 bf16
    u16* a2 = (u16*)(wbuf + 1280);                // 16*72 bf16 (skewed P)

    f32x4 acc[4];
    #pragma unroll
    for (int nb = 0; nb < 4; ++nb) acc[nb] = (f32x4){0.f, 0.f, 0.f, 0.f};
    float rsum[4] = {0.f, 0.f, 0.f, 0.f};

    // hoisted Q fragments (q pre-scaled by 0.125)
    const u16* qrow = q_bf + (size_t)((b << 10) + t0 + l15) * CC;
    short8 aq0 = *(const short8*)(qrow + quad * 8);
    short8 aq1 = *(const short8*)(qrow + 32 + quad * 8);

    // ---- content scores: 16x32 tile ----
    f32x4 sc[2];
    #pragma unroll
    for (int cb = 0; cb < 2; ++cb) {
        const u16* krow = k_bf + (size_t)((b << 10) + s0 + cb * 16 + l15) * CC;
        short8 kb0 = *(const short8*)(krow + quad * 8);
        short8 kb1 = *(const short8*)(krow + 32 + quad * 8);
        f32x4 a = {0.f, 0.f, 0.f, 0.f};
        a = MFMA16(aq0, kb0, a);
        a = MFMA16(aq1, kb1, a);
        sc[cb] = a;
    }

    // ---- relative band: 3 MFMAs kept in C-layout registers ----
    const int dbase = t0 - s0 - 31;
    f32x4 bnd[3];
    #pragma unroll
    for (int nb = 0; nb < 3; ++nb) {
        const u16* erow = embk_pad + (size_t)(dbase + 32 + nb * 16 + l15) * CC;
        short8 eb0 = *(const short8*)(erow + quad * 8);
        short8 eb1 = *(const short8*)(erow + 32 + quad * 8);
        f32x4 a = {0.f, 0.f, 0.f, 0.f};
        a = MFMA16(aq0, eb0, a);
        a = MFMA16(aq1, eb1, a);
        bnd[nb] = a;
    }

    // ---- band via cross-lane shuffles + masked p = exp(score) ----
    u16 pb0[4], pb1[4];
    #pragma unroll
    for (int r = 0; r < 4; ++r) {
        const int i = quad * 4 + r;
        const int u0 = 31 + i - l15;
        const int src = (quad << 4) | (u0 & 15);
        const float v0 = __shfl(bnd[0][r], src, 64);
        const float v1 = __shfl(bnd[1][r], src, 64);
        const float v2 = __shfl(bnd[2][r], src, 64);
        const bool hi = (u0 >= 32);
        {   // cb = 0: j = l15
            const float rb = hi ? v2 : v1;
            const int d = t0 - s0 + i - l15;
            float pv = (d >= 0) ? __expf(sc[0][r] + rb) : 0.f;
            pb0[r] = f2bf(pv);
            rsum[r] += bf2f(pb0[r]);
        }
        {   // cb = 1: j = 16+l15
            const float rb = hi ? v1 : v0;
            const int d = t0 - s0 + i - 16 - l15;
            float pv = (d >= 0) ? __expf(sc[1][r] + rb) : 0.f;
            pb1[r] = f2bf(pv);
            rsum[r] += bf2f(pb1[r]);
        }
    }

    // ---- write P: row-major (pt) and skewed (a2); in-wave DS order ----
    u32x4 z = {0u, 0u, 0u, 0u};
    #pragma unroll
    for (int e = 0; e < 3; ++e) {                  // 144 u32x4 = 16*72 u16
        int idx = lane + e * 64;
        if (idx < 144) ((u32x4*)a2)[idx] = z;
    }
    #pragma unroll
    for (int r = 0; r < 4; ++r) {
        const int i = quad * 4 + r;
        pt[i * 40 + l15] = pb0[r];
        pt[i * 40 + 16 + l15] = pb1[r];
        a2[i * 72 + (32 + i - l15)] = pb0[r];
        a2[i * 72 + (16 + i - l15)] = pb1[r];
    }

    // ---- y1 += P @ V ----
    short8 aP = *(const short8*)(pt + l15 * 40 + quad * 8);
    #pragma unroll
    for (int nb = 0; nb < 4; ++nb) {
        const u16* vrow = vT_bf + ((size_t)(b * CC + nb * 16 + l15) << 10) + s0;
        short8 bv = *(const short8*)(vrow + quad * 8);
        acc[nb] = MFMA16(aP, bv, acc[nb]);
    }

    // ---- y2 += skew(P) @ embv band ----
    const int dcol0 = t0 - s0;
    #pragma unroll
    for (int kk = 0; kk < 2; ++kk) {
        short8 a2f = *(const short8*)(a2 + l15 * 72 + kk * 32 + quad * 8);
        #pragma unroll
        for (int nb = 0; nb < 4; ++nb) {
            const u16* erow = embvT_pad + (size_t)(nb * 16 + l15) * 1088 + dcol0 + kk * 32 + quad * 8;
            short8 be = *(const short8*)erow;
            acc[nb] = MFMA16(a2f, be, acc[nb]);
        }
    }

    // ---- per-wave row-sum reduction; store L slot ----
    #pragma unroll
    for (int msk = 1; msk < 16; msk <<= 1)
        #pragma unroll
        for (int r = 0; r < 4; ++r) rsum[r] += __shfl_xor(rsum[r], msk, 64);
    const size_t pslot = (size_t)(b * 1056 + blockIdx.x);
    if (l15 == 0) {
        #pragma unroll
        for (int r = 0; r < 4; ++r) Lpart[pslot * 16 + quad * 4 + r] = rsum[r];
    }

    // ---- Y slot: C-layout -> LDS (in-wave) -> coalesced float4 stores ----
    float* ypw = (float*)(wbuf);                   // reuse, 4 KB
    #pragma unroll
    for (int nb = 0; nb < 4; ++nb)
        #pragma unroll
        for (int r = 0; r < 4; ++r)
            ypw[(quad * 4 + r) * 64 + nb * 16 + l15] = acc[nb][r];
    const size_t sbase = pslot << 10;
    #pragma unroll
    for (int k2 = 0; k2 < 4; ++k2) {
        float4 v = *(const float4*)&ypw[(lane + k2 * 64) * 4];
        *(float4*)&Ypart[sbase + (size_t)(lane + k2 * 64) * 4] = v;
    }
}

// ---------------------------------------------------------------------------
// K3: sum nst slots, normalize, Wproj MFMA epilogue. Grid (64, 8), 256 thr.
// Packed slot base: S(2h)=h(h+1), S(2h+1)=(h+1)^2.
// ---------------------------------------------------------------------------
__global__ __launch_bounds__(256) void norm_proj_kernel(const float* __restrict__ Ypart,
                                                        const float* __restrict__ Lpart,
                                                        const u16* __restrict__ Wproj_bf,
                                                        const float* __restrict__ bproj,
                                                        float* __restrict__ out) {
    const int b = blockIdx.y;
    const int tt = blockIdx.x;
    const int t0 = tt * 16;
    const int nst = (tt >> 1) + 1;
    const int h = tt >> 1;
    const int sbegin = (tt & 1) ? (h + 1) * (h + 1) : h * (h + 1);
    const int tid = threadIdx.x;
    const int w = tid >> 6, lane = tid & 63, quad = lane >> 4, l15 = lane & 15;

    __shared__ float Ls[16];
    __shared__ __align__(16) u16 yA[16 * 64];

    const size_t base = ((size_t)(b * 1056 + sbegin)) << 10;
    float4 Y = {0.f, 0.f, 0.f, 0.f};
    for (int s = 0; s < nst; ++s) {
        float4 v = *(const float4*)&Ypart[base + ((size_t)s << 10) + (size_t)tid * 4];
        Y.x += v.x; Y.y += v.y; Y.z += v.z; Y.w += v.w;
    }
    if (tid < 16) {
        float L = 0.f;
        for (int s = 0; s < nst; ++s)
            L += Lpart[(size_t)(b * 1056 + sbegin + s) * 16 + tid];
        Ls[tid] = L;
    }
    __syncthreads();

    const int i = tid >> 4, c0 = (tid * 4) & 63;
    const float inv = 1.0f / Ls[i];
    u16 y4[4] = { f2bf(Y.x * inv), f2bf(Y.y * inv), f2bf(Y.z * inv), f2bf(Y.w * inv) };
    *(unsigned long long*)&yA[i * 64 + c0] =
        (unsigned long long)y4[0] | ((unsigned long long)y4[1] << 16)
      | ((unsigned long long)y4[2] << 32) | ((unsigned long long)y4[3] << 48);
    __syncthreads();

    // proj: wave w -> output cols w*16 .. +15
    short8 a0 = *(const short8*)(yA + l15 * 64 + quad * 8);
    short8 a1 = *(const short8*)(yA + l15 * 64 + 32 + quad * 8);
    const u16* wrow = Wproj_bf + (size_t)(w * 16 + l15) * CC;
    short8 wb0 = *(const short8*)(wrow + quad * 8);
    short8 wb1 = *(const short8*)(wrow + 32 + quad * 8);
    f32x4 o = {0.f, 0.f, 0.f, 0.f};
    o = MFMA16(a0, wb0, o);
    o = MFMA16(a1, wb1, o);
    const float bias = bproj[w * 16 + l15];
    #pragma unroll
    for (int r = 0; r < 4; ++r)
        out[(size_t)((b << 10) + t0 + quad * 4 + r) * CC + w * 16 + l15] = o[r] + bias;
}

// ===========================================================================
// Fallback path (round-1 verified fp32 kernels) — used if ws_size < needed.
// ===========================================================================
__global__ __launch_bounds__(192) void qkv_kernel(const float* __restrict__ x,
                                                  const float* __restrict__ Wqkv,
                                                  const float* __restrict__ bqkv,
                                                  float* __restrict__ qkv) {
    __shared__ __align__(16) float xs[CC];
    const int row = blockIdx.x;
    const int j = threadIdx.x;
    if (j < CC) xs[j] = x[row * CC + j];
    __syncthreads();
    const float* w = Wqkv + j * CC;
    float acc = bqkv[j];
    #pragma unroll
    for (int c = 0; c < CC; c += 4) {
        float4 wq = *(const float4*)(w + c);
        float4 xq = *(const float4*)(xs + c);
        acc += wq.x * xq.x + wq.y * xq.y + wq.z * xq.z + wq.w * xq.w;
    }
    qkv[row * 192 + j] = acc;
}

__global__ __launch_bounds__(256) void attn_kernel(const float* __restrict__ qkv,
                                                   const float* __restrict__ embk,
                                                   const float* __restrict__ embv,
                                                   const float* __restrict__ Wproj,
                                                   const float* __restrict__ bproj,
                                                   float* __restrict__ out) {
    __shared__ __align__(16) float qs[CC];
    __shared__ __align__(16) float sc[TT];
    __shared__ float red[256];
    __shared__ float yred[4][CC];
    const int bt = blockIdx.x;
    const int b = bt >> 10, t = bt & (TT - 1);
    const int tid = threadIdx.x;
    if (tid < CC) qs[tid] = qkv[bt * 192 + tid];
    __syncthreads();
    float lmax = -1e30f;
    for (int s = tid; s <= t; s += 256) {
        const float* krow = qkv + (b * TT + s) * 192 + 64;
        const float* erow = embk + (t - s) * CC;
        float acc = 0.f;
        #pragma unroll
        for (int c = 0; c < CC; c += 4) {
            float4 kq = *(const float4*)(krow + c);
            float4 eq = *(const float4*)(erow + c);
            float4 qq = *(const float4*)(qs + c);
            acc += qq.x * (kq.x + eq.x) + qq.y * (kq.y + eq.y)
                 + qq.z * (kq.z + eq.z) + qq.w * (kq.w + eq.w);
        }
        acc *= 0.125f;
        sc[s] = acc;
        lmax = fmaxf(lmax, acc);
    }
    red[tid] = lmax; __syncthreads();
    for (int off = 128; off > 0; off >>= 1) { if (tid < off) red[tid] = fmaxf(red[tid], red[tid + off]); __syncthreads(); }
    const float m = red[0]; __syncthreads();
    float lsum = 0.f;
    for (int s = tid; s <= t; s += 256) { float e = __expf(sc[s] - m); sc[s] = e; lsum += e; }
    red[tid] = lsum; __syncthreads();
    for (int off = 128; off > 0; off >>= 1) { if (tid < off) red[tid] += red[tid + off]; __syncthreads(); }
    const float inv = 1.0f / red[0]; __syncthreads();
    const int c = tid & 63, g = tid >> 6;
    float acc = 0.f;
    for (int s = g; s <= t; s += 4) {
        float p = sc[s];
        float vv = qkv[(b * TT + s) * 192 + 128 + c];
        float ev = embv[(t - s) * CC + c];
        acc += p * (vv + ev);
    }
    yred[g][c] = acc * inv;
    __syncthreads();
    if (tid < CC) qs[tid] = yred[0][tid] + yred[1][tid] + yred[2][tid] + yred[3][tid];
    __syncthreads();
    if (tid < CC) {
        const float* w = Wproj + tid * CC;
        float o = bproj[tid];
        #pragma unroll
        for (int cc2 = 0; cc2 < CC; cc2 += 4) {
            float4 wq = *(const float4*)(w + cc2);
            float4 yq = *(const float4*)(qs + cc2);
            o += wq.x * yq.x + wq.y * yq.y + wq.z * yq.z + wq.w * yq.w;
        }
        out[bt * CC + tid] = o;
    }
}

extern "C" void kernel_launch(void* const* d_in, const int* in_sizes, int n_in,
                              void* d_out, int out_size, void* d_ws, size_t ws_size,
                              hipStream_t stream) {
    const float* x     = (const float*)d_in[0];
    const float* Wqkv  = (const float*)d_in[1];
    const float* bqkv  = (const float*)d_in[2];
    const float* embk  = (const float*)d_in[3];
    const float* embv  = (const float*)d_in[4];
    const float* Wproj = (const float*)d_in[5];
    const float* bproj = (const float*)d_in[6];
    float* out = (float*)d_out;

    if (ws_size < WS_NEED) {
        float* qkv = (float*)d_ws;
        qkv_kernel<<<BB * TT, 192, 0, stream>>>(x, Wqkv, bqkv, qkv);
        attn_kernel<<<BB * TT, 256, 0, stream>>>(qkv, embk, embv, Wproj, bproj, out);
        return;
    }

    char* ws = (char*)d_ws;
    u16* q_bf       = (u16*)(ws + OFF_QBF);
    u16* k_bf       = (u16*)(ws + OFF_KBF);
    u16* vT_bf      = (u16*)(ws + OFF_VT);
    u16* embk_pad   = (u16*)(ws + OFF_EKP);
    u16* embvT_pad  = (u16*)(ws + OFF_EVT);
    u16* Wproj_bf   = (u16*)(ws + OFF_WPROJ);
    float* Ypart    = (float*)(ws + OFF_YP);
    float* Lpart    = (float*)(ws + OFF_LP);

    qkv_prep_kernel<<<dim3(576, 3), 256, 0, stream>>>(x, Wqkv, bqkv, embk, embv, Wproj,
                                                      q_bf, k_bf, vT_bf, embk_pad, embvT_pad, Wproj_bf);
    attn_part_kernel<<<dim3(1056, 8), 64, 0, stream>>>(q_bf, k_bf, vT_bf, embk_pad, embvT_pad,
                                                       Ypart, Lpart);
    norm_proj_kernel<<<dim3(64, 8), 256, 0, stream>>>(Ypart, Lpart, Wproj_bf, bproj, out);
}

// Round 11
// 113.513 us; speedup vs baseline: 2.9335x; 1.0920x over previous
//
#include <hip/hip_runtime.h>
#include <math.h>

#define BB 8
#define TT 1024
#define CC 64

typedef float f32x4 __attribute__((ext_vector_type(4)));
typedef short short8 __attribute__((ext_vector_type(8)));
typedef unsigned int u32x4 __attribute__((ext_vector_type(4)));
typedef unsigned short u16;

static __device__ __forceinline__ u16 f2bf(float f) {
    union { float f; unsigned int u; } v; v.f = f;
    unsigned int r = v.u + 0x7fffu + ((v.u >> 16) & 1u);
    return (u16)(r >> 16);
}
static __device__ __forceinline__ float bf2f(u16 h) {
    union { unsigned int u; float f; } v; v.u = ((unsigned int)h) << 16; return v.f;
}
static __device__ __forceinline__ short8 pack8(const float* p) {
    float4 a = *(const float4*)p;
    float4 b = *(const float4*)(p + 4);
    short8 r;
    r[0] = (short)f2bf(a.x); r[1] = (short)f2bf(a.y); r[2] = (short)f2bf(a.z); r[3] = (short)f2bf(a.w);
    r[4] = (short)f2bf(b.x); r[5] = (short)f2bf(b.y); r[6] = (short)f2bf(b.z); r[7] = (short)f2bf(b.w);
    return r;
}

#define MFMA16(a, b, c) __builtin_amdgcn_mfma_f32_16x16x32_bf16((a), (b), (c), 0, 0, 0)

// Workspace layout (bytes)
#define OFF_QBF      ((size_t)0)             // q pre-scaled by 0.125
#define OFF_KBF      ((size_t)1048576)
#define OFF_VT       ((size_t)2097152)       // [b][c][t]
#define OFF_EKP      ((size_t)3145728)       // 1088*64 bf16 (rows d=-32..1055)
#define OFF_EVT      ((size_t)3284992)       // 64*1088 bf16 (cols d=-32..1055)
#define OFF_WPROJ    ((size_t)3424256)       // 64*64 bf16
#define OFF_YP       ((size_t)3432448)       // 8*160*1024 fp32 = 5242880
#define OFF_LP       ((size_t)8675328)       // 8*160*16 fp32 = 81920
#define WS_NEED      ((size_t)8757248)

// ---------------------------------------------------------------------------
// K1: qkv + prep. Grid (576, 3): x<512 -> qkv row-tile, y = oc group; one oc
// chunk per wave. x>=512 & y==0 -> pad fills. (Verified R6-R8 structure.)
// ---------------------------------------------------------------------------
__global__ __launch_bounds__(256) void qkv_prep_kernel(const float* __restrict__ x,
                                                       const float* __restrict__ Wqkv,
                                                       const float* __restrict__ bqkv,
                                                       const float* __restrict__ embk,
                                                       const float* __restrict__ embv,
                                                       const float* __restrict__ Wproj,
                                                       u16* __restrict__ q_bf,
                                                       u16* __restrict__ k_bf,
                                                       u16* __restrict__ vT_bf,
                                                       u16* __restrict__ embk_pad,
                                                       u16* __restrict__ embvT_pad,
                                                       u16* __restrict__ Wproj_bf) {
    const int blk = blockIdx.x;
    const int grp = blockIdx.y;
    const int tid = threadIdx.x;

    if (blk >= 512) {
        if (grp != 0) return;
        const int idx0 = (blk - 512) * 256 + tid;
        const int stride = 64 * 256;
        for (int i = idx0; i < 1088 * CC; i += stride) {
            int r = i >> 6, c = i & 63, d = r - 32;
            embk_pad[i] = (d >= 0 && d < TT) ? f2bf(embk[d * CC + c]) : (u16)0;
        }
        for (int i = idx0; i < CC * 1088; i += stride) {
            int c = i / 1088, col = i - c * 1088, d = col - 32;
            embvT_pad[i] = (d >= 0 && d < TT) ? f2bf(embv[d * CC + c]) : (u16)0;
        }
        for (int i = idx0; i < CC * CC; i += stride) Wproj_bf[i] = f2bf(Wproj[i]);
        return;
    }

    const int w = tid >> 6, lane = tid & 63, quad = lane >> 4, l15 = lane & 15;
    const int row0 = blk * 16;
    const int oc = grp * 4 + w;                 // 0..11
    __shared__ float vt[4][16][17];

    const float* xr = x + (size_t)(row0 + l15) * CC + quad * 8;
    short8 a0 = pack8(xr);
    short8 a1 = pack8(xr + 32);

    const float* wr = Wqkv + (size_t)(oc * 16 + l15) * CC + quad * 8;
    short8 b0 = pack8(wr);
    short8 b1 = pack8(wr + 32);
    f32x4 acc = {0.f, 0.f, 0.f, 0.f};
    acc = MFMA16(a0, b0, acc);
    acc = MFMA16(a1, b1, acc);
    const float bias = bqkv[oc * 16 + l15];

    if (oc < 4) {
        const int c = oc * 16 + l15;
        #pragma unroll
        for (int r = 0; r < 4; ++r)
            q_bf[(size_t)(row0 + quad * 4 + r) * CC + c] = f2bf((acc[r] + bias) * 0.125f);
    } else if (oc < 8) {
        const int c = (oc - 4) * 16 + l15;
        #pragma unroll
        for (int r = 0; r < 4; ++r)
            k_bf[(size_t)(row0 + quad * 4 + r) * CC + c] = f2bf(acc[r] + bias);
    } else {
        #pragma unroll
        for (int r = 0; r < 4; ++r) vt[w][quad * 4 + r][l15] = acc[r] + bias;
        const int c_l = lane >> 2;
        const int tbase = (lane & 3) * 4;
        const int b = row0 >> 10, t0v = row0 & (TT - 1);
        u16 p[4];
        #pragma unroll
        for (int tt2 = 0; tt2 < 4; ++tt2) p[tt2] = f2bf(vt[w][tbase + tt2][c_l]);
        unsigned long long pk = (unsigned long long)p[0] | ((unsigned long long)p[1] << 16)
                              | ((unsigned long long)p[2] << 32) | ((unsigned long long)p[3] << 48);
        *(unsigned long long*)&vT_bf[(size_t)(b * CC + (oc - 8) * 16 + c_l) * TT + t0v + tbase] = pk;
    }
}

// ---------------------------------------------------------------------------
// One s-tile of the verified R7/R8 attention body (shfl-band, fixed-max
// softmax). Accumulates unnormalized y into acc[4], row-sums into rsum[4].
// ---------------------------------------------------------------------------
static __device__ __forceinline__ void process_tile(int b, int t0, int s0,
                                                    int lane, int quad, int l15,
                                                    short8 aq0, short8 aq1,
                                                    const u16* __restrict__ k_bf,
                                                    const u16* __restrict__ embk_pad,
                                                    const u16* __restrict__ vT_bf,
                                                    const u16* __restrict__ embvT_pad,
                                                    u16* pt, u16* a2,
                                                    f32x4 acc[4], float rsum[4]) {
    // ---- content scores: 16x32 tile ----
    f32x4 sc[2];
    #pragma unroll
    for (int cb = 0; cb < 2; ++cb) {
        const u16* krow = k_bf + (size_t)((b << 10) + s0 + cb * 16 + l15) * CC;
        short8 kb0 = *(const short8*)(krow + quad * 8);
        short8 kb1 = *(const short8*)(krow + 32 + quad * 8);
        f32x4 a = {0.f, 0.f, 0.f, 0.f};
        a = MFMA16(aq0, kb0, a);
        a = MFMA16(aq1, kb1, a);
        sc[cb] = a;
    }

    // ---- relative band: 3 MFMAs kept in C-layout registers ----
    const int dbase = t0 - s0 - 31;
    f32x4 bnd[3];
    #pragma unroll
    for (int nb = 0; nb < 3; ++nb) {
        const u16* erow = embk_pad + (size_t)(dbase + 32 + nb * 16 + l15) * CC;
        short8 eb0 = *(const short8*)(erow + quad * 8);
        short8 eb1 = *(const short8*)(erow + 32 + quad * 8);
        f32x4 a = {0.f, 0.f, 0.f, 0.f};
        a = MFMA16(aq0, eb0, a);
        a = MFMA16(aq1, eb1, a);
        bnd[nb] = a;
    }

    // ---- band via cross-lane shuffles + masked p = exp(score) ----
    u16 pb0[4], pb1[4];
    #pragma unroll
    for (int r = 0; r < 4; ++r) {
        const int i = quad * 4 + r;
        const int u0 = 31 + i - l15;
        const int src = (quad << 4) | (u0 & 15);
        const float v0 = __shfl(bnd[0][r], src, 64);
        const float v1 = __shfl(bnd[1][r], src, 64);
        const float v2 = __shfl(bnd[2][r], src, 64);
        const bool hi = (u0 >= 32);
        {   // cb = 0: j = l15
            const float rb = hi ? v2 : v1;
            const int d = t0 - s0 + i - l15;
            float pv = (d >= 0) ? __expf(sc[0][r] + rb) : 0.f;
            pb0[r] = f2bf(pv);
            rsum[r] += bf2f(pb0[r]);
        }
        {   // cb = 1: j = 16+l15
            const float rb = hi ? v1 : v0;
            const int d = t0 - s0 + i - 16 - l15;
            float pv = (d >= 0) ? __expf(sc[1][r] + rb) : 0.f;
            pb1[r] = f2bf(pv);
            rsum[r] += bf2f(pb1[r]);
        }
    }

    // ---- write P: row-major (pt) and skewed (a2); in-wave DS order ----
    u32x4 z = {0u, 0u, 0u, 0u};
    #pragma unroll
    for (int e = 0; e < 3; ++e) {                  // 144 u32x4 = 16*72 u16
        int idx = lane + e * 64;
        if (idx < 144) ((u32x4*)a2)[idx] = z;
    }
    #pragma unroll
    for (int r = 0; r < 4; ++r) {
        const int i = quad * 4 + r;
        pt[i * 40 + l15] = pb0[r];
        pt[i * 40 + 16 + l15] = pb1[r];
        a2[i * 72 + (32 + i - l15)] = pb0[r];
        a2[i * 72 + (16 + i - l15)] = pb1[r];
    }

    // ---- y1 += P @ V ----
    short8 aP = *(const short8*)(pt + l15 * 40 + quad * 8);
    #pragma unroll
    for (int nb = 0; nb < 4; ++nb) {
        const u16* vrow = vT_bf + ((size_t)(b * CC + nb * 16 + l15) << 10) + s0;
        short8 bv = *(const short8*)(vrow + quad * 8);
        acc[nb] = MFMA16(aP, bv, acc[nb]);
    }

    // ---- y2 += skew(P) @ embv band ----
    const int dcol0 = t0 - s0;
    #pragma unroll
    for (int kk = 0; kk < 2; ++kk) {
        short8 a2f = *(const short8*)(a2 + l15 * 72 + kk * 32 + quad * 8);
        #pragma unroll
        for (int nb = 0; nb < 4; ++nb) {
            const u16* erow = embvT_pad + (size_t)(nb * 16 + l15) * 1088 + dcol0 + kk * 32 + quad * 8;
            short8 be = *(const short8*)erow;
            acc[nb] = MFMA16(a2f, be, acc[nb]);
        }
    }
}

// ---------------------------------------------------------------------------
// K2: attention partials, TWO s-tiles per wave (independent register/LDS
// instances interleaved for ILP — the chain is latency-bound, R8 used only
// 48 VGPRs). Grid (160, 8): block x -> (tt, slot), slot covers s-tiles
// slot*8 .. slot*8+7 (wave w: stA = slot*8+w, stB = slot*8+4+w).
// 4-wave LDS merge -> one unnormalized (Y 16x64 fp32, L 16) slot per block.
// nslots(tt) = ceil(nst/8) <= 4. No fences (R9 lesson), no min-waves bound
// (R4/R7 lesson).
// ---------------------------------------------------------------------------
#define WBSTRIDE 7168   // per-wave: [ptA 1280 | a2A 2304 | ptB 1280 | a2B 2304]

__global__ __launch_bounds__(256) void attn_part_kernel(const u16* __restrict__ q_bf,
                                                        const u16* __restrict__ k_bf,
                                                        const u16* __restrict__ vT_bf,
                                                        const u16* __restrict__ embk_pad,
                                                        const u16* __restrict__ embvT_pad,
                                                        float* __restrict__ Ypart,
                                                        float* __restrict__ Lpart) {
    const int b = blockIdx.y;
    // map flat x -> (tt, slot): per-tile slot count = ceil(nst/8) = ((tt>>1)+8)>>3
    int xx = blockIdx.x;
    int tt = 0, slot = 0;
    for (tt = 0; tt < 64; ++tt) {
        const int c = ((tt >> 1) + 8) >> 3;
        if (xx < c) { slot = xx; break; }
        xx -= c;
    }
    const int t0 = tt * 16;
    const int nst = (tt >> 1) + 1;

    const int tid = threadIdx.x;
    const int w = tid >> 6, lane = tid & 63, quad = lane >> 4, l15 = lane & 15;
    const int stA = slot * 8 + w;
    const int stB = slot * 8 + 4 + w;

    __shared__ __align__(16) char wbuf[4][WBSTRIDE];
    __shared__ float lpart[4][16];

    f32x4 acc[4];
    #pragma unroll
    for (int nb = 0; nb < 4; ++nb) acc[nb] = (f32x4){0.f, 0.f, 0.f, 0.f};
    float rsum[4] = {0.f, 0.f, 0.f, 0.f};

    // hoisted Q fragments (q pre-scaled by 0.125) — same t0 for both tiles
    const u16* qrow = q_bf + (size_t)((b << 10) + t0 + l15) * CC;
    short8 aq0 = *(const short8*)(qrow + quad * 8);
    short8 aq1 = *(const short8*)(qrow + 32 + quad * 8);

    if (stA < nst)
        process_tile(b, t0, stA * 32, lane, quad, l15, aq0, aq1,
                     k_bf, embk_pad, vT_bf, embvT_pad,
                     (u16*)(wbuf[w]), (u16*)(wbuf[w] + 1280), acc, rsum);
    if (stB < nst)
        process_tile(b, t0, stB * 32, lane, quad, l15, aq0, aq1,
                     k_bf, embk_pad, vT_bf, embvT_pad,
                     (u16*)(wbuf[w] + 3584), (u16*)(wbuf[w] + 4864), acc, rsum);

    // ---- per-wave row-sum reduction ----
    #pragma unroll
    for (int msk = 1; msk < 16; msk <<= 1)
        #pragma unroll
        for (int r = 0; r < 4; ++r) rsum[r] += __shfl_xor(rsum[r], msk, 64);
    if (l15 == 0) {
        #pragma unroll
        for (int r = 0; r < 4; ++r) lpart[w][quad * 4 + r] = rsum[r];
    }

    // ---- wave partial Y -> unioned per-wave LDS region ----
    float* ypw = (float*)(wbuf[w]);
    #pragma unroll
    for (int nb = 0; nb < 4; ++nb)
        #pragma unroll
        for (int r = 0; r < 4; ++r)
            ypw[(quad * 4 + r) * 64 + nb * 16 + l15] = acc[nb][r];
    __syncthreads();

    // ---- merge 4 wave partials, store slot (unnormalized) ----
    const int i4 = tid >> 4, c04 = (tid * 4) & 63;
    const size_t pslot = (size_t)(b * 160 + blockIdx.x);
    {
        float4 Y;
        Y.x = ((float*)(wbuf[0]))[i4 * 64 + c04]     + ((float*)(wbuf[1]))[i4 * 64 + c04]
            + ((float*)(wbuf[2]))[i4 * 64 + c04]     + ((float*)(wbuf[3]))[i4 * 64 + c04];
        Y.y = ((float*)(wbuf[0]))[i4 * 64 + c04 + 1] + ((float*)(wbuf[1]))[i4 * 64 + c04 + 1]
            + ((float*)(wbuf[2]))[i4 * 64 + c04 + 1] + ((float*)(wbuf[3]))[i4 * 64 + c04 + 1];
        Y.z = ((float*)(wbuf[0]))[i4 * 64 + c04 + 2] + ((float*)(wbuf[1]))[i4 * 64 + c04 + 2]
            + ((float*)(wbuf[2]))[i4 * 64 + c04 + 2] + ((float*)(wbuf[3]))[i4 * 64 + c04 + 2];
        Y.w = ((float*)(wbuf[0]))[i4 * 64 + c04 + 3] + ((float*)(wbuf[1]))[i4 * 64 + c04 + 3]
            + ((float*)(wbuf[2]))[i4 * 64 + c04 + 3] + ((float*)(wbuf[3]))[i4 * 64 + c04 + 3];
        *(float4*)&Ypart[(pslot << 10) + (size_t)tid * 4] = Y;
    }
    if (tid < 16)
        Lpart[pslot * 16 + tid] = lpart[0][tid] + lpart[1][tid] + lpart[2][tid] + lpart[3][tid];
}

// ---------------------------------------------------------------------------
// K3: sum slots (<=4), normalize, Wproj MFMA epilogue. Grid (64, 8), 256 thr.
// ---------------------------------------------------------------------------
__global__ __launch_bounds__(256) void norm_proj_kernel(const float* __restrict__ Ypart,
                                                        const float* __restrict__ Lpart,
                                                        const u16* __restrict__ Wproj_bf,
                                                        const float* __restrict__ bproj,
                                                        float* __restrict__ out) {
    const int b = blockIdx.y;
    const int tt = blockIdx.x;
    const int t0 = tt * 16;
    const int nslots = ((tt >> 1) + 8) >> 3;
    int sbegin = 0;
    for (int t2 = 0; t2 < tt; ++t2) sbegin += ((t2 >> 1) + 8) >> 3;
    const int tid = threadIdx.x;
    const int w = tid >> 6, lane = tid & 63, quad = lane >> 4, l15 = lane & 15;

    __shared__ float Ls[16];
    __shared__ __align__(16) u16 yA[16 * 64];

    const size_t base = ((size_t)(b * 160 + sbegin)) << 10;
    float4 Y = {0.f, 0.f, 0.f, 0.f};
    for (int s = 0; s < nslots; ++s) {
        float4 v = *(const float4*)&Ypart[base + ((size_t)s << 10) + (size_t)tid * 4];
        Y.x += v.x; Y.y += v.y; Y.z += v.z; Y.w += v.w;
    }
    if (tid < 16) {
        float L = 0.f;
        for (int s = 0; s < nslots; ++s)
            L += Lpart[(size_t)(b * 160 + sbegin + s) * 16 + tid];
        Ls[tid] = L;
    }
    __syncthreads();

    const int i = tid >> 4, c0 = (tid * 4) & 63;
    const float inv = 1.0f / Ls[i];
    u16 y4[4] = { f2bf(Y.x * inv), f2bf(Y.y * inv), f2bf(Y.z * inv), f2bf(Y.w * inv) };
    *(unsigned long long*)&yA[i * 64 + c0] =
        (unsigned long long)y4[0] | ((unsigned long long)y4[1] << 16)
      | ((unsigned long long)y4[2] << 32) | ((unsigned long long)y4[3] << 48);
    __syncthreads();

    // proj: wave w -> output cols w*16 .. +15
    short8 a0 = *(const short8*)(yA + l15 * 64 + quad * 8);
    short8 a1 = *(const short8*)(yA + l15 * 64 + 32 + quad * 8);
    const u16* wrow = Wproj_bf + (size_t)(w * 16 + l15) * CC;
    short8 wb0 = *(const short8*)(wrow + quad * 8);
    short8 wb1 = *(const short8*)(wrow + 32 + quad * 8);
    f32x4 o = {0.f, 0.f, 0.f, 0.f};
    o = MFMA16(a0, wb0, o);
    o = MFMA16(a1, wb1, o);
    const float bias = bproj[w * 16 + l15];
    #pragma unroll
    for (int r = 0; r < 4; ++r)
        out[(size_t)((b << 10) + t0 + quad * 4 + r) * CC + w * 16 + l15] = o[r] + bias;
}

// ===========================================================================
// Fallback path (round-1 verified fp32 kernels) — used if ws_size < needed.
// ===========================================================================
__global__ __launch_bounds__(192) void qkv_kernel(const float* __restrict__ x,
                                                  const float* __restrict__ Wqkv,
                                                  const float* __restrict__ bqkv,
                                                  float* __restrict__ qkv) {
    __shared__ __align__(16) float xs[CC];
    const int row = blockIdx.x;
    const int j = threadIdx.x;
    if (j < CC) xs[j] = x[row * CC + j];
    __syncthreads();
    const float* w = Wqkv + j * CC;
    float acc = bqkv[j];
    #pragma unroll
    for (int c = 0; c < CC; c += 4) {
        float4 wq = *(const float4*)(w + c);
        float4 xq = *(const float4*)(xs + c);
        acc += wq.x * xq.x + wq.y * xq.y + wq.z * xq.z + wq.w * xq.w;
    }
    qkv[row * 192 + j] = acc;
}

__global__ __launch_bounds__(256) void attn_kernel(const float* __restrict__ qkv,
                                                   const float* __restrict__ embk,
                                                   const float* __restrict__ embv,
                                                   const float* __restrict__ Wproj,
                                                   const float* __restrict__ bproj,
                                                   float* __restrict__ out) {
    __shared__ __align__(16) float qs[CC];
    __shared__ __align__(16) float sc[TT];
    __shared__ float red[256];
    __shared__ float yred[4][CC];
    const int bt = blockIdx.x;
    const int b = bt >> 10, t = bt & (TT - 1);
    const int tid = threadIdx.x;
    if (tid < CC) qs[tid] = qkv[bt * 192 + tid];
    __syncthreads();
    float lmax = -1e30f;
    for (int s = tid; s <= t; s += 256) {
        const float* krow = qkv + (b * TT + s) * 192 + 64;
        const float* erow = embk + (t - s) * CC;
        float acc = 0.f;
        #pragma unroll
        for (int c = 0; c < CC; c += 4) {
            float4 kq = *(const float4*)(krow + c);
            float4 eq = *(const float4*)(erow + c);
            float4 qq = *(const float4*)(qs + c);
            acc += qq.x * (kq.x + eq.x) + qq.y * (kq.y + eq.y)
                 + qq.z * (kq.z + eq.z) + qq.w * (kq.w + eq.w);
        }
        acc *= 0.125f;
        sc[s] = acc;
        lmax = fmaxf(lmax, acc);
    }
    red[tid] = lmax; __syncthreads();
    for (int off = 128; off > 0; off >>= 1) { if (tid < off) red[tid] = fmaxf(red[tid], red[tid + off]); __syncthreads(); }
    const float m = red[0]; __syncthreads();
    float lsum = 0.f;
    for (int s = tid; s <= t; s += 256) { float e = __expf(sc[s] - m); sc[s] = e; lsum += e; }
    red[tid] = lsum; __syncthreads();
    for (int off = 128; off > 0; off >>= 1) { if (tid < off) red[tid] += red[tid + off]; __syncthreads(); }
    const float inv = 1.0f / red[0]; __syncthreads();
    const int c = tid & 63, g = tid >> 6;
    float acc = 0.f;
    for (int s = g; s <= t; s += 4) {
        float p = sc[s];
        float vv = qkv[(b * TT + s) * 192 + 128 + c];
        float ev = embv[(t - s) * CC + c];
        acc += p * (vv + ev);
    }
    yred[g][c] = acc * inv;
    __syncthreads();
    if (tid < CC) qs[tid] = yred[0][tid] + yred[1][tid] + yred[2][tid] + yred[3][tid];
    __syncthreads();
    if (tid < CC) {
        const float* w = Wproj + tid * CC;
        float o = bproj[tid];
        #pragma unroll
        for (int cc2 = 0; cc2 < CC; cc2 += 4) {
            float4 wq = *(const float4*)(w + cc2);
            float4 yq = *(const float4*)(qs + cc2);
            o += wq.x * yq.x + wq.y * yq.y + wq.z * yq.z + wq.w * yq.w;
        }
        out[bt * CC + tid] = o;
    }
}

extern "C" void kernel_launch(void* const* d_in, const int* in_sizes, int n_in,
                              void* d_out, int out_size, void* d_ws, size_t ws_size,
                              hipStream_t stream) {
    const float* x     = (const float*)d_in[0];
    const float* Wqkv  = (const float*)d_in[1];
    const float* bqkv  = (const float*)d_in[2];
    const float* embk  = (const float*)d_in[3];
    const float* embv  = (const float*)d_in[4];
    const float* Wproj = (const float*)d_in[5];
    const float* bproj = (const float*)d_in[6];
    float* out = (float*)d_out;

    if (ws_size < WS_NEED) {
        float* qkv = (float*)d_ws;
        qkv_kernel<<<BB * TT, 192, 0, stream>>>(x, Wqkv, bqkv, qkv);
        attn_kernel<<<BB * TT, 256, 0, stream>>>(qkv, embk, embv, Wproj, bproj, out);
        return;
    }

    char* ws = (char*)d_ws;
    u16* q_bf       = (u16*)(ws + OFF_QBF);
    u16* k_bf       = (u16*)(ws + OFF_KBF);
    u16* vT_bf      = (u16*)(ws + OFF_VT);
    u16* embk_pad   = (u16*)(ws + OFF_EKP);
    u16* embvT_pad  = (u16*)(ws + OFF_EVT);
    u16* Wproj_bf   = (u16*)(ws + OFF_WPROJ);
    float* Ypart    = (float*)(ws + OFF_YP);
    float* Lpart    = (float*)(ws + OFF_LP);

    qkv_prep_kernel<<<dim3(576, 3), 256, 0, stream>>>(x, Wqkv, bqkv, embk, embv, Wproj,
                                                      q_bf, k_bf, vT_bf, embk_pad, embvT_pad, Wproj_bf);
    attn_part_kernel<<<dim3(160, 8), 256, 0, stream>>>(q_bf, k_bf, vT_bf, embk_pad, embvT_pad,
                                                       Ypart, Lpart);
    norm_proj_kernel<<<dim3(64, 8), 256, 0, stream>>>(Ypart, Lpart, Wproj_bf, bproj, out);
}

// Round 12
// 111.147 us; speedup vs baseline: 2.9960x; 1.0213x over previous
//
#include <hip/hip_runtime.h>
#include <hip/hip_bf16.h>
#include <math.h>

#define BB 8
#define TT 1024
#define CC 64

typedef float f32x4 __attribute__((ext_vector_type(4)));
typedef short short8 __attribute__((ext_vector_type(8)));
typedef unsigned int u32x4 __attribute__((ext_vector_type(4)));
typedef unsigned short u16;

static __device__ __forceinline__ u16 f2bf(float f) {
    union { float f; unsigned int u; } v; v.f = f;
    unsigned int r = v.u + 0x7fffu + ((v.u >> 16) & 1u);
    return (u16)(r >> 16);
}
static __device__ __forceinline__ float bf2f(u16 h) {
    union { unsigned int u; float f; } v; v.u = ((unsigned int)h) << 16; return v.f;
}
// packed RNE f32x2 -> bf16x2 (v_cvt_pk_bf16_f32); same rounding as f2bf
static __device__ __forceinline__ unsigned int pk2(float x, float y) {
    __hip_bfloat162 t = __float22bfloat162_rn(float2{x, y});
    union { __hip_bfloat162 b; unsigned int u; } v; v.b = t; return v.u;
}
static __device__ __forceinline__ short8 pack8(const float* p) {
    float4 a = *(const float4*)p;
    float4 b = *(const float4*)(p + 4);
    union { unsigned int u[4]; short8 s; } r;
    r.u[0] = pk2(a.x, a.y);
    r.u[1] = pk2(a.z, a.w);
    r.u[2] = pk2(b.x, b.y);
    r.u[3] = pk2(b.z, b.w);
    return r.s;
}

#define MFMA16(a, b, c) __builtin_amdgcn_mfma_f32_16x16x32_bf16((a), (b), (c), 0, 0, 0)

// Workspace layout (bytes)
#define OFF_QBF      ((size_t)0)             // q pre-scaled by 0.125
#define OFF_KBF      ((size_t)1048576)
#define OFF_VT       ((size_t)2097152)       // [b][c][t]
#define OFF_EKP      ((size_t)3145728)       // 1088*64 bf16 (rows d=-32..1055)
#define OFF_EVT      ((size_t)3284992)       // 64*1088 bf16 (cols d=-32..1055)
#define OFF_WPROJ    ((size_t)3424256)       // 64*64 bf16
#define OFF_YP       ((size_t)3432448)       // 8*64*8*1024 fp32 = 16777216
#define OFF_LP       ((size_t)20209664)      // 8*64*8*16 fp32 = 262144
#define WS_NEED      ((size_t)20471808)

// ---------------------------------------------------------------------------
// K1: qkv + prep. Grid (576, 3): x<512 -> qkv row-tile, y = oc group; one oc
// chunk per wave. x>=512 & y==0 -> pad fills. (Verified R6-R8 structure;
// packed v_cvt_pk_bf16_f32 conversions.)
// ---------------------------------------------------------------------------
__global__ __launch_bounds__(256) void qkv_prep_kernel(const float* __restrict__ x,
                                                       const float* __restrict__ Wqkv,
                                                       const float* __restrict__ bqkv,
                                                       const float* __restrict__ embk,
                                                       const float* __restrict__ embv,
                                                       const float* __restrict__ Wproj,
                                                       u16* __restrict__ q_bf,
                                                       u16* __restrict__ k_bf,
                                                       u16* __restrict__ vT_bf,
                                                       u16* __restrict__ embk_pad,
                                                       u16* __restrict__ embvT_pad,
                                                       u16* __restrict__ Wproj_bf) {
    const int blk = blockIdx.x;
    const int grp = blockIdx.y;
    const int tid = threadIdx.x;

    if (blk >= 512) {
        if (grp != 0) return;
        const int idx0 = (blk - 512) * 256 + tid;
        const int stride = 64 * 256;
        for (int i = idx0; i < 1088 * CC; i += stride) {
            int r = i >> 6, c = i & 63, d = r - 32;
            embk_pad[i] = (d >= 0 && d < TT) ? f2bf(embk[d * CC + c]) : (u16)0;
        }
        for (int i = idx0; i < CC * 1088; i += stride) {
            int c = i / 1088, col = i - c * 1088, d = col - 32;
            embvT_pad[i] = (d >= 0 && d < TT) ? f2bf(embv[d * CC + c]) : (u16)0;
        }
        for (int i = idx0; i < CC * CC; i += stride) Wproj_bf[i] = f2bf(Wproj[i]);
        return;
    }

    const int w = tid >> 6, lane = tid & 63, quad = lane >> 4, l15 = lane & 15;
    const int row0 = blk * 16;
    const int oc = grp * 4 + w;                 // 0..11
    __shared__ float vt[4][16][17];

    const float* xr = x + (size_t)(row0 + l15) * CC + quad * 8;
    short8 a0 = pack8(xr);
    short8 a1 = pack8(xr + 32);

    const float* wr = Wqkv + (size_t)(oc * 16 + l15) * CC + quad * 8;
    short8 b0 = pack8(wr);
    short8 b1 = pack8(wr + 32);
    f32x4 acc = {0.f, 0.f, 0.f, 0.f};
    acc = MFMA16(a0, b0, acc);
    acc = MFMA16(a1, b1, acc);
    const float bias = bqkv[oc * 16 + l15];

    if (oc < 4) {
        const int c = oc * 16 + l15;
        #pragma unroll
        for (int r = 0; r < 4; ++r)
            q_bf[(size_t)(row0 + quad * 4 + r) * CC + c] = f2bf((acc[r] + bias) * 0.125f);
    } else if (oc < 8) {
        const int c = (oc - 4) * 16 + l15;
        #pragma unroll
        for (int r = 0; r < 4; ++r)
            k_bf[(size_t)(row0 + quad * 4 + r) * CC + c] = f2bf(acc[r] + bias);
    } else {
        #pragma unroll
        for (int r = 0; r < 4; ++r) vt[w][quad * 4 + r][l15] = acc[r] + bias;
        const int c_l = lane >> 2;
        const int tbase = (lane & 3) * 4;
        const int b = row0 >> 10, t0v = row0 & (TT - 1);
        unsigned int lo = pk2(vt[w][tbase + 0][c_l], vt[w][tbase + 1][c_l]);
        unsigned int hi = pk2(vt[w][tbase + 2][c_l], vt[w][tbase + 3][c_l]);
        unsigned long long pk = (unsigned long long)lo | ((unsigned long long)hi << 32);
        *(unsigned long long*)&vT_bf[(size_t)(b * CC + (oc - 8) * 16 + c_l) * TT + t0v + tbase] = pk;
    }
}

// ---------------------------------------------------------------------------
// K2: attention partials (exact R8 structure — best measured: 110.6 total).
// Grid (288, 8): block x -> (tt, slot) via cumulative ceil(nst/4) map; each
// of the 4 waves does exactly ONE s-tile (flat dependence graph, all global
// loads issue up front). 17 KB LDS + VGPR~48 -> 8 blocks/CU = full 32-wave
// occupancy. Writes Ypart[b][tt][slot] (16x64 fp32) and Lpart (16 fp32);
// deterministic slots, no atomics, no fences (R9 lesson).
// ---------------------------------------------------------------------------
#define WBSTRIDE 4160   // per-wave LDS: pt(1280) + a2(2304) = 3584; merge 4096

__global__ __launch_bounds__(256) void attn_part_kernel(const u16* __restrict__ q_bf,
                                                        const u16* __restrict__ k_bf,
                                                        const u16* __restrict__ vT_bf,
                                                        const u16* __restrict__ embk_pad,
                                                        const u16* __restrict__ embvT_pad,
                                                        float* __restrict__ Ypart,
                                                        float* __restrict__ Lpart) {
    const int b = blockIdx.y;
    // map flat x -> (tt, slot): per-tile slot count = ceil(nst/4) = ((tt>>1)+4)>>2
    int xx = blockIdx.x;
    int tt = 0, slot = 0;
    for (tt = 0; tt < 64; ++tt) {
        const int c = ((tt >> 1) + 4) >> 2;
        if (xx < c) { slot = xx; break; }
        xx -= c;
    }
    const int t0 = tt * 16;
    const int nst = (t0 >> 5) + 1;

    const int tid = threadIdx.x;
    const int w = tid >> 6, lane = tid & 63, quad = lane >> 4, l15 = lane & 15;
    const int st = slot * 4 + w;
    const bool active = (st < nst);

    __shared__ __align__(16) char wbuf[4][WBSTRIDE];
    __shared__ float lpart[4][16];

    u16* pt = (u16*)(wbuf[w]);                    // 16*40 bf16
    u16* a2 = (u16*)(wbuf[w] + 1280);             // 16*72 bf16 (skewed P)

    f32x4 acc[4];
    #pragma unroll
    for (int nb = 0; nb < 4; ++nb) acc[nb] = (f32x4){0.f, 0.f, 0.f, 0.f};
    float rsum[4] = {0.f, 0.f, 0.f, 0.f};

    if (active) {
        const int s0 = st * 32;

        // hoisted Q fragments (q pre-scaled by 0.125)
        const u16* qrow = q_bf + (size_t)((b << 10) + t0 + l15) * CC;
        short8 aq0 = *(const short8*)(qrow + quad * 8);
        short8 aq1 = *(const short8*)(qrow + 32 + quad * 8);

        // ---- content scores: 16x32 tile ----
        f32x4 sc[2];
        #pragma unroll
        for (int cb = 0; cb < 2; ++cb) {
            const u16* krow = k_bf + (size_t)((b << 10) + s0 + cb * 16 + l15) * CC;
            short8 kb0 = *(const short8*)(krow + quad * 8);
            short8 kb1 = *(const short8*)(krow + 32 + quad * 8);
            f32x4 a = {0.f, 0.f, 0.f, 0.f};
            a = MFMA16(aq0, kb0, a);
            a = MFMA16(aq1, kb1, a);
            sc[cb] = a;
        }

        // ---- relative band: 3 MFMAs kept in C-layout registers ----
        const int dbase = t0 - s0 - 31;
        f32x4 bnd[3];
        #pragma unroll
        for (int nb = 0; nb < 3; ++nb) {
            const u16* erow = embk_pad + (size_t)(dbase + 32 + nb * 16 + l15) * CC;
            short8 eb0 = *(const short8*)(erow + quad * 8);
            short8 eb1 = *(const short8*)(erow + 32 + quad * 8);
            f32x4 a = {0.f, 0.f, 0.f, 0.f};
            a = MFMA16(aq0, eb0, a);
            a = MFMA16(aq1, eb1, a);
            bnd[nb] = a;
        }

        // ---- band via cross-lane shuffles + masked p = exp(score) ----
        u16 pb0[4], pb1[4];
        #pragma unroll
        for (int r = 0; r < 4; ++r) {
            const int i = quad * 4 + r;
            const int u0 = 31 + i - l15;
            const int src = (quad << 4) | (u0 & 15);
            const float v0 = __shfl(bnd[0][r], src, 64);
            const float v1 = __shfl(bnd[1][r], src, 64);
            const float v2 = __shfl(bnd[2][r], src, 64);
            const bool hi = (u0 >= 32);
            {   // cb = 0: j = l15
                const float rb = hi ? v2 : v1;
                const int d = t0 - s0 + i - l15;
                float pv = (d >= 0) ? __expf(sc[0][r] + rb) : 0.f;
                pb0[r] = f2bf(pv);
                rsum[r] += bf2f(pb0[r]);
            }
            {   // cb = 1: j = 16+l15
                const float rb = hi ? v1 : v0;
                const int d = t0 - s0 + i - 16 - l15;
                float pv = (d >= 0) ? __expf(sc[1][r] + rb) : 0.f;
                pb1[r] = f2bf(pv);
                rsum[r] += bf2f(pb1[r]);
            }
        }

        // ---- write P: row-major (pt) and skewed (a2); in-wave DS order ----
        u32x4 z = {0u, 0u, 0u, 0u};
        #pragma unroll
        for (int e = 0; e < 3; ++e) {              // 144 u32x4 = 16*72 u16
            int idx = lane + e * 64;
            if (idx < 144) ((u32x4*)a2)[idx] = z;
        }
        #pragma unroll
        for (int r = 0; r < 4; ++r) {
            const int i = quad * 4 + r;
            pt[i * 40 + l15] = pb0[r];
            pt[i * 40 + 16 + l15] = pb1[r];
            a2[i * 72 + (32 + i - l15)] = pb0[r];
            a2[i * 72 + (16 + i - l15)] = pb1[r];
        }

        // ---- y1 += P @ V ----
        short8 aP = *(const short8*)(pt + l15 * 40 + quad * 8);
        #pragma unroll
        for (int nb = 0; nb < 4; ++nb) {
            const u16* vrow = vT_bf + ((size_t)(b * CC + nb * 16 + l15) << 10) + s0;
            short8 bv = *(const short8*)(vrow + quad * 8);
            acc[nb] = MFMA16(aP, bv, acc[nb]);
        }

        // ---- y2 += skew(P) @ embv band ----
        const int dcol0 = t0 - s0;
        #pragma unroll
        for (int kk = 0; kk < 2; ++kk) {
            short8 a2f = *(const short8*)(a2 + l15 * 72 + kk * 32 + quad * 8);
            #pragma unroll
            for (int nb = 0; nb < 4; ++nb) {
                const u16* erow = embvT_pad + (size_t)(nb * 16 + l15) * 1088 + dcol0 + kk * 32 + quad * 8;
                short8 be = *(const short8*)erow;
                acc[nb] = MFMA16(a2f, be, acc[nb]);
            }
        }
    }

    // ---- per-wave row-sum reduction ----
    #pragma unroll
    for (int msk = 1; msk < 16; msk <<= 1)
        #pragma unroll
        for (int r = 0; r < 4; ++r) rsum[r] += __shfl_xor(rsum[r], msk, 64);
    if (l15 == 0) {
        #pragma unroll
        for (int r = 0; r < 4; ++r) lpart[w][quad * 4 + r] = rsum[r];
    }

    // ---- wave partial Y -> unioned per-wave LDS region ----
    float* ypw = (float*)(wbuf[w]);
    #pragma unroll
    for (int nb = 0; nb < 4; ++nb)
        #pragma unroll
        for (int r = 0; r < 4; ++r)
            ypw[(quad * 4 + r) * 64 + nb * 16 + l15] = acc[nb][r];
    __syncthreads();

    // ---- merge 4 wave partials, store slot (unnormalized) ----
    const int i4 = tid >> 4, c04 = (tid * 4) & 63;
    const size_t sbase = ((size_t)((b * 64 + tt) * 8 + slot)) << 10;
    {
        float4 Y;
        Y.x = ((float*)(wbuf[0]))[i4 * 64 + c04]     + ((float*)(wbuf[1]))[i4 * 64 + c04]
            + ((float*)(wbuf[2]))[i4 * 64 + c04]     + ((float*)(wbuf[3]))[i4 * 64 + c04];
        Y.y = ((float*)(wbuf[0]))[i4 * 64 + c04 + 1] + ((float*)(wbuf[1]))[i4 * 64 + c04 + 1]
            + ((float*)(wbuf[2]))[i4 * 64 + c04 + 1] + ((float*)(wbuf[3]))[i4 * 64 + c04 + 1];
        Y.z = ((float*)(wbuf[0]))[i4 * 64 + c04 + 2] + ((float*)(wbuf[1]))[i4 * 64 + c04 + 2]
            + ((float*)(wbuf[2]))[i4 * 64 + c04 + 2] + ((float*)(wbuf[3]))[i4 * 64 + c04 + 2];
        Y.w = ((float*)(wbuf[0]))[i4 * 64 + c04 + 3] + ((float*)(wbuf[1]))[i4 * 64 + c04 + 3]
            + ((float*)(wbuf[2]))[i4 * 64 + c04 + 3] + ((float*)(wbuf[3]))[i4 * 64 + c04 + 3];
        *(float4*)&Ypart[sbase + (size_t)tid * 4] = Y;
    }
    if (tid < 16)
        Lpart[((size_t)((b * 64 + tt) * 8 + slot)) * 16 + tid] =
            lpart[0][tid] + lpart[1][tid] + lpart[2][tid] + lpart[3][tid];
}

// ---------------------------------------------------------------------------
// K3: sum slots, normalize, Wproj MFMA epilogue. Grid (64, 8), 256 thr.
// ---------------------------------------------------------------------------
__global__ __launch_bounds__(256) void norm_proj_kernel(const float* __restrict__ Ypart,
                                                        const float* __restrict__ Lpart,
                                                        const u16* __restrict__ Wproj_bf,
                                                        const float* __restrict__ bproj,
                                                        float* __restrict__ out) {
    const int b = blockIdx.y;
    const int tt = blockIdx.x;
    const int t0 = tt * 16;
    const int nslots = ((tt >> 1) + 4) >> 2;      // ceil(nst/4)
    const int tid = threadIdx.x;
    const int w = tid >> 6, lane = tid & 63, quad = lane >> 4, l15 = lane & 15;

    __shared__ float Ls[16];
    __shared__ __align__(16) u16 yA[16 * 64];

    // hoist Wproj fragments (independent of Ypart loads)
    const u16* wrow = Wproj_bf + (size_t)(w * 16 + l15) * CC;
    short8 wb0 = *(const short8*)(wrow + quad * 8);
    short8 wb1 = *(const short8*)(wrow + 32 + quad * 8);

    const size_t base = ((size_t)((b * 64 + tt) * 8)) << 10;
    float4 Y = {0.f, 0.f, 0.f, 0.f};
    for (int s = 0; s < nslots; ++s) {
        float4 v = *(const float4*)&Ypart[base + ((size_t)s << 10) + (size_t)tid * 4];
        Y.x += v.x; Y.y += v.y; Y.z += v.z; Y.w += v.w;
    }
    if (tid < 16) {
        float L = 0.f;
        for (int s = 0; s < nslots; ++s)
            L += Lpart[((size_t)((b * 64 + tt) * 8 + s)) * 16 + tid];
        Ls[tid] = L;
    }
    __syncthreads();

    const int i = tid >> 4, c0 = (tid * 4) & 63;
    const float inv = 1.0f / Ls[i];
    unsigned int lo = pk2(Y.x * inv, Y.y * inv);
    unsigned int hi = pk2(Y.z * inv, Y.w * inv);
    *(unsigned long long*)&yA[i * 64 + c0] =
        (unsigned long long)lo | ((unsigned long long)hi << 32);
    __syncthreads();

    // proj: wave w -> output cols w*16 .. +15
    short8 a0 = *(const short8*)(yA + l15 * 64 + quad * 8);
    short8 a1 = *(const short8*)(yA + l15 * 64 + 32 + quad * 8);
    f32x4 o = {0.f, 0.f, 0.f, 0.f};
    o = MFMA16(a0, wb0, o);
    o = MFMA16(a1, wb1, o);
    const float bias = bproj[w * 16 + l15];
    #pragma unroll
    for (int r = 0; r < 4; ++r)
        out[(size_t)((b << 10) + t0 + quad * 4 + r) * CC + w * 16 + l15] = o[r] + bias;
}

// ===========================================================================
// Fallback path (round-1 verified fp32 kernels) — used if ws_size < needed.
// ===========================================================================
__global__ __launch_bounds__(192) void qkv_kernel(const float* __restrict__ x,
                                                  const float* __restrict__ Wqkv,
                                                  const float* __restrict__ bqkv,
                                                  float* __restrict__ qkv) {
    __shared__ __align__(16) float xs[CC];
    const int row = blockIdx.x;
    const int j = threadIdx.x;
    if (j < CC) xs[j] = x[row * CC + j];
    __syncthreads();
    const float* w = Wqkv + j * CC;
    float acc = bqkv[j];
    #pragma unroll
    for (int c = 0; c < CC; c += 4) {
        float4 wq = *(const float4*)(w + c);
        float4 xq = *(const float4*)(xs + c);
        acc += wq.x * xq.x + wq.y * xq.y + wq.z * xq.z + wq.w * xq.w;
    }
    qkv[row * 192 + j] = acc;
}

__global__ __launch_bounds__(256) void attn_kernel(const float* __restrict__ qkv,
                                                   const float* __restrict__ embk,
                                                   const float* __restrict__ embv,
                                                   const float* __restrict__ Wproj,
                                                   const float* __restrict__ bproj,
                                                   float* __restrict__ out) {
    __shared__ __align__(16) float qs[CC];
    __shared__ __align__(16) float sc[TT];
    __shared__ float red[256];
    __shared__ float yred[4][CC];
    const int bt = blockIdx.x;
    const int b = bt >> 10, t = bt & (TT - 1);
    const int tid = threadIdx.x;
    if (tid < CC) qs[tid] = qkv[bt * 192 + tid];
    __syncthreads();
    float lmax = -1e30f;
    for (int s = tid; s <= t; s += 256) {
        const float* krow = qkv + (b * TT + s) * 192 + 64;
        const float* erow = embk + (t - s) * CC;
        float acc = 0.f;
        #pragma unroll
        for (int c = 0; c < CC; c += 4) {
            float4 kq = *(const float4*)(krow + c);
            float4 eq = *(const float4*)(erow + c);
            float4 qq = *(const float4*)(qs + c);
            acc += qq.x * (kq.x + eq.x) + qq.y * (kq.y + eq.y)
                 + qq.z * (kq.z + eq.z) + qq.w * (kq.w + eq.w);
        }
        acc *= 0.125f;
        sc[s] = acc;
        lmax = fmaxf(lmax, acc);
    }
    red[tid] = lmax; __syncthreads();
    for (int off = 128; off > 0; off >>= 1) { if (tid < off) red[tid] = fmaxf(red[tid], red[tid + off]); __syncthreads(); }
    const float m = red[0]; __syncthreads();
    float lsum = 0.f;
    for (int s = tid; s <= t; s += 256) { float e = __expf(sc[s] - m); sc[s] = e; lsum += e; }
    red[tid] = lsum; __syncthreads();
    for (int off = 128; off > 0; off >>= 1) { if (tid < off) red[tid] += red[tid + off]; __syncthreads(); }
    const float inv = 1.0f / red[0]; __syncthreads();
    const int c = tid & 63, g = tid >> 6;
    float acc = 0.f;
    for (int s = g; s <= t; s += 4) {
        float p = sc[s];
        float vv = qkv[(b * TT + s) * 192 + 128 + c];
        float ev = embv[(t - s) * CC + c];
        acc += p * (vv + ev);
    }
    yred[g][c] = acc * inv;
    __syncthreads();
    if (tid < CC) qs[tid] = yred[0][tid] + yred[1][tid] + yred[2][tid] + yred[3][tid];
    __syncthreads();
    if (tid < CC) {
        const float* w = Wproj + tid * CC;
        float o = bproj[tid];
        #pragma unroll
        for (int cc2 = 0; cc2 < CC; cc2 += 4) {
            float4 wq = *(const float4*)(w + cc2);
            float4 yq = *(const float4*)(qs + cc2);
            o += wq.x * yq.x + wq.y * yq.y + wq.z * yq.z + wq.w * yq.w;
        }
        out[bt * CC + tid] = o;
    }
}

extern "C" void kernel_launch(void* const* d_in, const int* in_sizes, int n_in,
                              void* d_out, int out_size, void* d_ws, size_t ws_size,
                              hipStream_t stream) {
    const float* x     = (const float*)d_in[0];
    const float* Wqkv  = (const float*)d_in[1];
    const float* bqkv  = (const float*)d_in[2];
    const float* embk  = (const float*)d_in[3];
    const float* embv  = (const float*)d_in[4];
    const float* Wproj = (const float*)d_in[5];
    const float* bproj = (const float*)d_in[6];
    float* out = (float*)d_out;

    if (ws_size < WS_NEED) {
        float* qkv = (float*)d_ws;
        qkv_kernel<<<BB * TT, 192, 0, stream>>>(x, Wqkv, bqkv, qkv);
        attn_kernel<<<BB * TT, 256, 0, stream>>>(qkv, embk, embv, Wproj, bproj, out);
        return;
    }

    char* ws = (char*)d_ws;
    u16* q_bf       = (u16*)(ws + OFF_QBF);
    u16* k_bf       = (u16*)(ws + OFF_KBF);
    u16* vT_bf      = (u16*)(ws + OFF_VT);
    u16* embk_pad   = (u16*)(ws + OFF_EKP);
    u16* embvT_pad  = (u16*)(ws + OFF_EVT);
    u16* Wproj_bf   = (u16*)(ws + OFF_WPROJ);
    float* Ypart    = (float*)(ws + OFF_YP);
    float* Lpart    = (float*)(ws + OFF_LP);

    qkv_prep_kernel<<<dim3(576, 3), 256, 0, stream>>>(x, Wqkv, bqkv, embk, embv, Wproj,
                                                      q_bf, k_bf, vT_bf, embk_pad, embvT_pad, Wproj_bf);
    attn_part_kernel<<<dim3(288, 8), 256, 0, stream>>>(q_bf, k_bf, vT_bf, embk_pad, embvT_pad,
                                                       Ypart, Lpart);
    norm_proj_kernel<<<dim3(64, 8), 256, 0, stream>>>(Ypart, Lpart, Wproj_bf, bproj, out);
}